// Round 4
// baseline (75.953 us; speedup 1.0000x reference)
//
#include <hip/hip_runtime.h>
#include <math.h>

#define N_KCS 5000
#define TT    100
#define BB    512

__device__ __forceinline__ float sigmoidf(float x) {
    return 1.0f / (1.0f + expf(-x));
}

// Single fused kernel, one workgroup per batch row.
// Sequential scan replaced by parallel per-kc chain resolution (chains have
// expected length ~1 for T=100 draws from 5000 kcs). All pristine-state reads
// are hoisted into registers so probs-write and state-override share one
// barrier phase: 4 __syncthreads total, 1 launch.
__global__ __launch_bounds__(256) void bkt_kernel(
    const int*   __restrict__ prev_kc,
    const int*   __restrict__ curr_kc,
    const int*   __restrict__ prev_corr,
    const float* __restrict__ logits,     // (N_KCS, 5) row-major
    float*       __restrict__ probs_out,  // (B, T)
    float*       __restrict__ state_out)  // (B, N_KCS)
{
    __shared__ float state[N_KCS];                       // 20 KB
    __shared__ int   pk_s[TT], ck_s[TT], nxt_s[TT];
    __shared__ float po0_s[TT], po1_s[TT], pp0_s[TT], pp1_s[TT];
    __shared__ float pred_s[TT];

    const int b    = blockIdx.x;
    const int tid  = threadIdx.x;
    const int base = b * TT;

    // stage indices + init state row
    if (tid < TT) {
        pk_s[tid] = prev_kc[base + tid];
        ck_s[tid] = curr_kc[base + tid];
    }
    for (int k = tid; k < N_KCS; k += 256) {
        state[k] = sigmoidf(logits[k * 5 + 4]);
    }
    __syncthreads();                                     // S1

    const int  t   = tid;
    const bool act = (t >= 1 && t < TT);
    int   lst  = -1;     // last t' <= t with pk[t'] == ck[t]
    bool  head = true;   // no t' <  t with pk[t'] == pk[t]
    float s_pk_init = 0.f, s_ck_init = 0.f;              // pristine reads
    float cp2 = 0.f, cp3 = 0.f;

    if (act) {
        const int mypk = pk_s[t];
        const int myck = ck_s[t];
        const int c    = prev_corr[base + t];

        // state-independent per-step constants
        float pp2 = sigmoidf(logits[mypk * 5 + 2]);
        float pp3 = sigmoidf(logits[mypk * 5 + 3]);
        pp0_s[t] = sigmoidf(logits[mypk * 5 + 0]);
        pp1_s[t] = sigmoidf(logits[mypk * 5 + 1]);
        cp2 = sigmoidf(logits[myck * 5 + 2]);
        cp3 = sigmoidf(logits[myck * 5 + 3]);
        // pch^c * (1-pch)^(1-c), c in {0,1} == select (bit-exact)
        po0_s[t] = c ? pp2 : (1.0f - pp2);
        po1_s[t] = c ? pp3 : (1.0f - pp3);

        // pristine state reads -> registers (state is unmodified until S3+)
        s_pk_init = state[mypk];
        s_ck_init = state[myck];

        // parallel linkage: scan all step indices (LDS broadcast reads)
        int nxt = -1;
        for (int tp = 1; tp < TT; ++tp) {
            int p = pk_s[tp];
            if (p == mypk) {
                if (tp < t)                    head = false;
                else if (tp > t && nxt == -1)  nxt  = tp;
            }
            if (p == myck && tp <= t) lst = tp;   // increasing tp -> max
        }
        nxt_s[t] = nxt;
    }

    float pc0 = 0.f;
    if (t == 0) {
        int   ck0 = ck_s[0];
        float c2  = sigmoidf(logits[ck0 * 5 + 2]);
        float c3  = sigmoidf(logits[ck0 * 5 + 3]);
        float cs0 = state[ck0];
        pc0 = c2 * (1.0f - cs0) + c3 * cs0;
    }
    __syncthreads();                                     // S2: po/pp/nxt ready

    // chain walk: head lanes evaluate their kc-chain sequentially
    // (arithmetic identical to the reference scan step)
    if (act && head) {
        float s = s_pk_init;
        int   u = t;
        while (u != -1) {
            float num        = po1_s[u] * s;
            float filt       = num / (po0_s[u] * (1.0f - s) + num);
            float predictive = pp0_s[u] * (1.0f - filt) + (1.0f - pp1_s[u]) * filt;
            pred_s[u] = predictive;
            s = predictive;
            u = nxt_s[u];
        }
    }
    __syncthreads();                                     // S3: pred_s ready

    // probs write + tail state override in one phase (no state reads here:
    // cs comes from registers or pred_s)
    if (t == 0) probs_out[base] = pc0;
    if (act) {
        float cs = (lst == -1) ? s_ck_init : pred_s[lst];
        probs_out[base + t] = cp2 * (1.0f - cs) + cp3 * cs;
        if (nxt_s[t] == -1) state[pk_s[t]] = pred_s[t];
    }
    __syncthreads();                                     // S4: overrides done

    // coalesced float4 writeback of final state
    float* out_row = state_out + (size_t)b * N_KCS;
    for (int k = tid * 4; k < N_KCS; k += 256 * 4) {
        *(float4*)&out_row[k] = *(const float4*)&state[k];
    }
}

extern "C" void kernel_launch(void* const* d_in, const int* in_sizes, int n_in,
                              void* d_out, int out_size, void* d_ws, size_t ws_size,
                              hipStream_t stream) {
    const int*   prev_kc   = (const int*)d_in[0];
    const int*   curr_kc   = (const int*)d_in[1];
    const int*   prev_corr = (const int*)d_in[2];
    const float* logits    = (const float*)d_in[3];

    float* out     = (float*)d_out;
    float* probs   = out;                 // B*T floats
    float* state_f = out + BB * TT;       // B*N_KCS floats

    bkt_kernel<<<BB, 256, 0, stream>>>(prev_kc, curr_kc, prev_corr, logits,
                                       probs, state_f);
}